// Round 3
// baseline (5289.525 us; speedup 1.0000x reference)
//
#include <hip/hip_runtime.h>
#include <math.h>

#define B_ 1024
#define T_ 128
#define H_ 2048
#define C_ 10

typedef __bf16 bf16_t;
typedef __bf16 bf16x8 __attribute__((ext_vector_type(8)));
typedef __bf16 bf16x4 __attribute__((ext_vector_type(4)));
typedef float f32x4 __attribute__((ext_vector_type(4)));

// Static device storage (fully rewritten every call, in dependency order):
// bf16 hidden-state ping-pong (8 MB), bf16 W_hh^T (8 MB).
__device__ __align__(16) bf16_t g_hb[2][(size_t)B_ * H_];
__device__ __align__(16) bf16_t g_whhT[(size_t)H_ * H_];

__device__ __forceinline__ void gload16(const bf16_t* g, bf16_t* l) {
    __builtin_amdgcn_global_load_lds(
        (const __attribute__((address_space(1))) void*)g,
        (__attribute__((address_space(3))) void*)l, 16, 0, 0);
}

// One-time: W_hhT[n][k] = bf16(W_hh[k][n]) — B operand must be K-contiguous.
__global__ __launch_bounds__(256) void prep_whhT(const float* __restrict__ Whh) {
    __shared__ float tile[32][33];
    const int i  = threadIdx.x >> 3;        // 0..31
    const int j4 = (threadIdx.x & 7) * 4;   // 0..28
    const int r0 = blockIdx.y * 32;         // k block (input rows)
    const int c0 = blockIdx.x * 32;         // n block (input cols)
    f32x4 v = *(const f32x4*)(Whh + (size_t)(r0 + i) * H_ + c0 + j4);
    tile[i][j4 + 0] = v[0]; tile[i][j4 + 1] = v[1];
    tile[i][j4 + 2] = v[2]; tile[i][j4 + 3] = v[3];
    __syncthreads();
    bf16x4 o;
#pragma unroll
    for (int r = 0; r < 4; ++r) o[r] = (bf16_t)tile[j4 + r][i];
    *(bf16x4*)&g_whhT[(size_t)(c0 + i) * H_ + r0 + j4] = o;
}

// t = 0: h = tanh(x[:,0]*W_hx + b_h)  (h0 == 0) -> bf16
__global__ __launch_bounds__(256) void rnn_init(const float* __restrict__ x,
                                                const float* __restrict__ Whx,
                                                const float* __restrict__ bh) {
    const int gid = blockIdx.x * 256 + threadIdx.x;   // each does 4 cols
    const int row = gid >> 9;
    const int col = (gid & 511) << 2;
    const float xv = x[(size_t)row * T_];
    f32x4 w = *(const f32x4*)&Whx[col];
    f32x4 b = *(const f32x4*)&bh[col];
    bf16x4 o;
#pragma unroll
    for (int j = 0; j < 4; ++j) o[j] = (bf16_t)tanhf(fmaf(xv, w[j], b[j]));
    *(bf16x4*)&g_hb[0][(size_t)row * H_ + col] = o;
}

// Fused RNN step: h[db] = tanh(h[sb] @ W_hh + x[:,t]*W_hx + b_h), bf16 out.
// 64(M) x 128(N) block tile, full K=2048, BK=32, 256 threads = 4 waves of
// 32x64 (2x2 acc of 16x16x32 bf16 MFMA). LDS double-buffered, one barrier
// per iter, async global_load_lds staging overlapped with MFMA.
// Grid (x=bn=16, y=bm=16): same-bn blocks land on the same XCD (bn%8) so the
// per-XCD 1MB B-slice stays L2-resident across the 16 bm re-reads.
__global__ __launch_bounds__(256) void rnn_step(const float* __restrict__ x,
                                                const float* __restrict__ Whx,
                                                const float* __restrict__ bh,
                                                int t, int sb, int db) {
    __shared__ __align__(16) bf16_t As[2][64 * 32];    // 4 KB each
    __shared__ __align__(16) bf16_t Bs[2][128 * 32];   // 8 KB each

    const int tid  = threadIdx.x;
    const int lane = tid & 63;
    const int wave = tid >> 6;
    const int bn = blockIdx.x, bm = blockIdx.y;
    const int wm = (wave & 1) * 32, wn = (wave >> 1) * 64;
    const int fr = lane & 15, fq = lane >> 4;

    const bf16_t* __restrict__ A = g_hb[sb];
    const int srow = tid >> 2;              // 0..63
    const int scol = (tid & 3) * 8;         // k chunk within BK
    const bf16_t* ga = A      + (size_t)(bm * 64 + srow) * H_ + scol;
    const bf16_t* gb = g_whhT + (size_t)(bn * 128 + srow) * H_ + scol;

    // stage buffer 0
    gload16(ga,           &As[0][tid * 8]);
    gload16(gb,           &Bs[0][tid * 8]);
    gload16(gb + 64 * H_, &Bs[0][(tid + 256) * 8]);

    f32x4 acc[2][4];
#pragma unroll
    for (int i = 0; i < 2; ++i)
#pragma unroll
        for (int j = 0; j < 4; ++j) acc[i][j] = (f32x4)(0.f);

    int buf = 0;
    for (int it = 0; it < 64; ++it) {
        __syncthreads();                    // drains staging of `buf`
        if (it + 1 < 64) {                  // async-stage next tile into buf^1
            ga += 32; gb += 32;
            const int nb = buf ^ 1;
            gload16(ga,           &As[nb][tid * 8]);
            gload16(gb,           &Bs[nb][tid * 8]);
            gload16(gb + 64 * H_, &Bs[nb][(tid + 256) * 8]);
        }
        bf16x8 af[2], bfv[4];
#pragma unroll
        for (int i = 0; i < 2; ++i)
            af[i] = *(const bf16x8*)&As[buf][(wm + i * 16 + fr) * 32 + fq * 8];
#pragma unroll
        for (int j = 0; j < 4; ++j)
            bfv[j] = *(const bf16x8*)&Bs[buf][(wn + j * 16 + fr) * 32 + fq * 8];
#pragma unroll
        for (int i = 0; i < 2; ++i)
#pragma unroll
            for (int j = 0; j < 4; ++j)
                acc[i][j] = __builtin_amdgcn_mfma_f32_16x16x32_bf16(
                    af[i], bfv[j], acc[i][j], 0, 0, 0);
        buf ^= 1;
    }

    // epilogue: + x_t*W_hx + b_h, tanh, bf16 store
    bf16_t* __restrict__ hn = g_hb[db];
    float xv[2][4];
#pragma unroll
    for (int i = 0; i < 2; ++i) {
        const int row0 = bm * 64 + wm + i * 16 + fq * 4;
#pragma unroll
        for (int r = 0; r < 4; ++r) xv[i][r] = x[(size_t)(row0 + r) * T_ + t];
    }
#pragma unroll
    for (int j = 0; j < 4; ++j) {
        const int col = bn * 128 + wn + j * 16 + fr;
        const float wv = Whx[col];
        const float bv = bh[col];
#pragma unroll
        for (int i = 0; i < 2; ++i) {
            const int row0 = bm * 64 + wm + i * 16 + fq * 4;
#pragma unroll
            for (int r = 0; r < 4; ++r)
                hn[(size_t)(row0 + r) * H_ + col] =
                    (bf16_t)tanhf(acc[i][j][r] + xv[i][r] * wv + bv);
        }
    }
}

// p = h_T @ W_ph + b_p : one wave per batch row, fp32 accumulate.
__global__ __launch_bounds__(64) void rnn_proj(const float* __restrict__ Wph,
                                               const float* __restrict__ bp,
                                               float* __restrict__ out, int sb) {
    const int b = blockIdx.x;
    const int l = threadIdx.x;
    const bf16_t* h = g_hb[sb] + (size_t)b * H_;
    float acc[C_];
#pragma unroll
    for (int c = 0; c < C_; ++c) acc[c] = 0.f;
    for (int k = l; k < H_; k += 64) {
        const float hv = (float)h[k];
#pragma unroll
        for (int c = 0; c < C_; ++c)
            acc[c] = fmaf(hv, Wph[k * C_ + c], acc[c]);
    }
#pragma unroll
    for (int off = 32; off > 0; off >>= 1)
#pragma unroll
        for (int c = 0; c < C_; ++c) acc[c] += __shfl_down(acc[c], off);
    if (l == 0) {
#pragma unroll
        for (int c = 0; c < C_; ++c) out[b * C_ + c] = acc[c] + bp[c];
    }
}

extern "C" void kernel_launch(void* const* d_in, const int* in_sizes, int n_in,
                              void* d_out, int out_size, void* d_ws, size_t ws_size,
                              hipStream_t stream) {
    const float* x   = (const float*)d_in[0];   // [1024,128]
    const float* Whx = (const float*)d_in[1];   // [1,2048]
    const float* Whh = (const float*)d_in[2];   // [2048,2048]
    const float* bh  = (const float*)d_in[3];   // [2048]
    const float* Wph = (const float*)d_in[4];   // [2048,10]
    const float* bp  = (const float*)d_in[5];   // [1,10]
    float* out = (float*)d_out;                 // [1024,10]

    prep_whhT<<<dim3(64, 64), 256, 0, stream>>>(Whh);
    rnn_init<<<(B_ * H_ / 4) / 256, 256, 0, stream>>>(x, Whx, bh);

    int src = 0;
    for (int t = 1; t < T_; ++t) {
        rnn_step<<<dim3(16, 16), 256, 0, stream>>>(x, Whx, bh, t, src, 1 - src);
        src = 1 - src;
    }
    rnn_proj<<<B_, 64, 0, stream>>>(Wph, bp, out, src);
}

// Round 4
// 4065.217 us; speedup vs baseline: 1.3012x; 1.3012x over previous
//
#include <hip/hip_runtime.h>
#include <math.h>

#define B_ 1024
#define T_ 128
#define H_ 2048
#define C_ 10

typedef __bf16 bf16_t;
typedef __bf16 bf16x8 __attribute__((ext_vector_type(8)));
typedef __bf16 bf16x4 __attribute__((ext_vector_type(4)));
typedef float f32x4 __attribute__((ext_vector_type(4)));

// Static device storage (fully rewritten every call, in dependency order):
// bf16 hidden-state ping-pong (8 MB), bf16 W_hh^T (8 MB).
__device__ __align__(16) bf16_t g_hb[2][(size_t)B_ * H_];
__device__ __align__(16) bf16_t g_whhT[(size_t)H_ * H_];

__device__ __forceinline__ void gload16(const bf16_t* g, bf16_t* l) {
    __builtin_amdgcn_global_load_lds(
        (const __attribute__((address_space(1))) void*)g,
        (__attribute__((address_space(3))) void*)l, 16, 0, 0);
}

// One-time: W_hhT[n][k] = bf16(W_hh[k][n]) — B operand must be K-contiguous.
__global__ __launch_bounds__(256) void prep_whhT(const float* __restrict__ Whh) {
    __shared__ float tile[32][33];
    const int i  = threadIdx.x >> 3;        // 0..31
    const int j4 = (threadIdx.x & 7) * 4;   // 0..28
    const int r0 = blockIdx.y * 32;         // k block (input rows)
    const int c0 = blockIdx.x * 32;         // n block (input cols)
    f32x4 v = *(const f32x4*)(Whh + (size_t)(r0 + i) * H_ + c0 + j4);
    tile[i][j4 + 0] = v[0]; tile[i][j4 + 1] = v[1];
    tile[i][j4 + 2] = v[2]; tile[i][j4 + 3] = v[3];
    __syncthreads();
    bf16x4 o;
#pragma unroll
    for (int r = 0; r < 4; ++r) o[r] = (bf16_t)tile[j4 + r][i];
    *(bf16x4*)&g_whhT[(size_t)(c0 + i) * H_ + r0 + j4] = o;
}

// t = 0: h = tanh(x[:,0]*W_hx + b_h)  (h0 == 0) -> bf16
__global__ __launch_bounds__(256) void rnn_init(const float* __restrict__ x,
                                                const float* __restrict__ Whx,
                                                const float* __restrict__ bh) {
    const int gid = blockIdx.x * 256 + threadIdx.x;   // each does 4 cols
    const int row = gid >> 9;
    const int col = (gid & 511) << 2;
    const float xv = x[(size_t)row * T_];
    f32x4 w = *(const f32x4*)&Whx[col];
    f32x4 b = *(const f32x4*)&bh[col];
    bf16x4 o;
#pragma unroll
    for (int j = 0; j < 4; ++j) o[j] = (bf16_t)tanhf(fmaf(xv, w[j], b[j]));
    *(bf16x4*)&g_hb[0][(size_t)row * H_ + col] = o;
}

// Fused RNN step: h[db] = tanh(h[sb] @ W_hh + x[:,t]*W_hx + b_h), bf16 out.
// 64x64 block tile, BK=64 (32 iters), 512 blocks -> 2 blocks/CU so a second
// block's waves cover each block's barrier drain. 4 waves of 32x32 (2x2 acc).
// LDS is XOR-swizzled in the k-chunk index so fragment ds_read_b128s are
// conflict-free while keeping the lane-linear layout global_load_lds needs.
__global__ __launch_bounds__(256) void rnn_step(const float* __restrict__ x,
                                                const float* __restrict__ Whx,
                                                const float* __restrict__ bh,
                                                int t, int sb, int db) {
    __shared__ __align__(16) bf16_t As[2][64 * 64];   // 8 KB each
    __shared__ __align__(16) bf16_t Bs[2][64 * 64];

    const int tid  = threadIdx.x;
    const int lane = tid & 63;
    const int wave = tid >> 6;
    // XCD swizzle: li%8 = XCD; each XCD owns bn in {r,r+8,r+16,r+24} for all bm
    const int li = blockIdx.x;
    const int bn = (li & 7) + ((li >> 3) & 3) * 8;    // 0..31
    const int bm = li >> 5;                           // 0..15

    const int wm = (wave & 1) * 32, wn = (wave >> 1) * 32;
    const int fr = lane & 15, fq = lane >> 4;

    // staging: 64 rows x 64 k per tile; thread t handles rows srow, srow+32,
    // k-chunk (8 elems) swizzled by row for bank-conflict-free frag reads.
    const int srow = tid >> 3;              // 0..31
    const int klin = tid & 7;               // linear chunk slot in LDS
    const int kc   = klin ^ (srow & 7);     // which global chunk lands there
    const bf16_t* ga = g_hb[sb] + (size_t)(bm * 64 + srow) * H_ + kc * 8;
    const bf16_t* gb = g_whhT  + (size_t)(bn * 64 + srow) * H_ + kc * 8;

    gload16(ga,           &As[0][tid * 8]);
    gload16(ga + 32 * H_, &As[0][(tid + 256) * 8]);
    gload16(gb,           &Bs[0][tid * 8]);
    gload16(gb + 32 * H_, &Bs[0][(tid + 256) * 8]);

    f32x4 acc[2][2];
#pragma unroll
    for (int i = 0; i < 2; ++i)
#pragma unroll
        for (int j = 0; j < 2; ++j) acc[i][j] = (f32x4)(0.f);

    // frag LDS offsets (elems): row*64 + (c8 ^ (row&7))*8, c8 = cc*4 + fq
    const int arow0 = wm + fr, brow0 = wn + fr;
    int aoff[2][2], boff[2][2];
#pragma unroll
    for (int i = 0; i < 2; ++i)
#pragma unroll
        for (int cc = 0; cc < 2; ++cc) {
            const int ar = arow0 + i * 16, br = brow0 + i * 16;
            aoff[i][cc] = ar * 64 + (((cc * 4 + fq) ^ (ar & 7)) * 8);
            boff[i][cc] = br * 64 + (((cc * 4 + fq) ^ (br & 7)) * 8);
        }

    int buf = 0;
    for (int it = 0; it < 32; ++it) {
        __syncthreads();                    // drains staging of `buf`
        if (it + 1 < 32) {                  // async-stage next tile into buf^1
            ga += 64; gb += 64;
            const int nb = buf ^ 1;
            gload16(ga,           &As[nb][tid * 8]);
            gload16(ga + 32 * H_, &As[nb][(tid + 256) * 8]);
            gload16(gb,           &Bs[nb][tid * 8]);
            gload16(gb + 32 * H_, &Bs[nb][(tid + 256) * 8]);
        }
        bf16x8 af[2][2], bfv[2][2];
#pragma unroll
        for (int i = 0; i < 2; ++i)
#pragma unroll
            for (int cc = 0; cc < 2; ++cc) {
                af[i][cc]  = *(const bf16x8*)&As[buf][aoff[i][cc]];
                bfv[i][cc] = *(const bf16x8*)&Bs[buf][boff[i][cc]];
            }
#pragma unroll
        for (int cc = 0; cc < 2; ++cc)
#pragma unroll
            for (int i = 0; i < 2; ++i)
#pragma unroll
                for (int j = 0; j < 2; ++j)
                    acc[i][j] = __builtin_amdgcn_mfma_f32_16x16x32_bf16(
                        af[i][cc], bfv[j][cc], acc[i][j], 0, 0, 0);
        buf ^= 1;
    }

    // epilogue: + x_t*W_hx + b_h, tanh, bf16 store
    bf16_t* __restrict__ hn = g_hb[db];
    float xv[2][4];
#pragma unroll
    for (int i = 0; i < 2; ++i) {
        const int row0 = bm * 64 + wm + i * 16 + fq * 4;
#pragma unroll
        for (int r = 0; r < 4; ++r) xv[i][r] = x[(size_t)(row0 + r) * T_ + t];
    }
#pragma unroll
    for (int j = 0; j < 2; ++j) {
        const int col = bn * 64 + wn + j * 16 + fr;
        const float wv = Whx[col];
        const float bv = bh[col];
#pragma unroll
        for (int i = 0; i < 2; ++i) {
            const int row0 = bm * 64 + wm + i * 16 + fq * 4;
#pragma unroll
            for (int r = 0; r < 4; ++r)
                hn[(size_t)(row0 + r) * H_ + col] =
                    (bf16_t)tanhf(acc[i][j][r] + xv[i][r] * wv + bv);
        }
    }
}

// p = h_T @ W_ph + b_p : one wave per batch row, fp32 accumulate.
__global__ __launch_bounds__(64) void rnn_proj(const float* __restrict__ Wph,
                                               const float* __restrict__ bp,
                                               float* __restrict__ out, int sb) {
    const int b = blockIdx.x;
    const int l = threadIdx.x;
    const bf16_t* h = g_hb[sb] + (size_t)b * H_;
    float acc[C_];
#pragma unroll
    for (int c = 0; c < C_; ++c) acc[c] = 0.f;
    for (int k = l; k < H_; k += 64) {
        const float hv = (float)h[k];
#pragma unroll
        for (int c = 0; c < C_; ++c)
            acc[c] = fmaf(hv, Wph[k * C_ + c], acc[c]);
    }
#pragma unroll
    for (int off = 32; off > 0; off >>= 1)
#pragma unroll
        for (int c = 0; c < C_; ++c) acc[c] += __shfl_down(acc[c], off);
    if (l == 0) {
#pragma unroll
        for (int c = 0; c < C_; ++c) out[b * C_ + c] = acc[c] + bp[c];
    }
}

extern "C" void kernel_launch(void* const* d_in, const int* in_sizes, int n_in,
                              void* d_out, int out_size, void* d_ws, size_t ws_size,
                              hipStream_t stream) {
    const float* x   = (const float*)d_in[0];   // [1024,128]
    const float* Whx = (const float*)d_in[1];   // [1,2048]
    const float* Whh = (const float*)d_in[2];   // [2048,2048]
    const float* bh  = (const float*)d_in[3];   // [2048]
    const float* Wph = (const float*)d_in[4];   // [2048,10]
    const float* bp  = (const float*)d_in[5];   // [1,10]
    float* out = (float*)d_out;                 // [1024,10]

    prep_whhT<<<dim3(64, 64), 256, 0, stream>>>(Whh);
    rnn_init<<<(B_ * H_ / 4) / 256, 256, 0, stream>>>(x, Whx, bh);

    int src = 0;
    for (int t = 1; t < T_; ++t) {
        rnn_step<<<512, 256, 0, stream>>>(x, Whx, bh, t, src, 1 - src);
        src = 1 - src;
    }
    rnn_proj<<<B_, 64, 0, stream>>>(Wph, bp, out, src);
}

// Round 5
// 3035.914 us; speedup vs baseline: 1.7423x; 1.3390x over previous
//
#include <hip/hip_runtime.h>
#include <math.h>

#define B_ 1024
#define T_ 128
#define H_ 2048
#define C_ 10

typedef __bf16 bf16_t;
typedef __bf16 bf16x8 __attribute__((ext_vector_type(8)));
typedef __bf16 bf16x4 __attribute__((ext_vector_type(4)));
typedef float f32x4 __attribute__((ext_vector_type(4)));

// Static device storage (fully rewritten every call, in dependency order):
// bf16 hidden-state ping-pong (8 MB), bf16 W_hh^T (8 MB).
__device__ __align__(16) bf16_t g_hb[2][(size_t)B_ * H_];
__device__ __align__(16) bf16_t g_whhT[(size_t)H_ * H_];

__device__ __forceinline__ void gload16(const bf16_t* g, bf16_t* l) {
    __builtin_amdgcn_global_load_lds(
        (const __attribute__((address_space(1))) void*)g,
        (__attribute__((address_space(3))) void*)l, 16, 0, 0);
}

// Raw barrier with counted vmcnt: does NOT drain the in-flight pipeline
// stages (unlike __syncthreads, whose fence forces vmcnt(0)).
template <int VM>
__device__ __forceinline__ void wait_vm_barrier() {
    asm volatile("s_waitcnt vmcnt(%0)\n\ts_barrier" :: "n"(VM) : "memory");
}

// One-time: W_hhT[n][k] = bf16(W_hh[k][n]) — B operand must be K-contiguous.
__global__ __launch_bounds__(256) void prep_whhT(const float* __restrict__ Whh) {
    __shared__ float tile[32][33];
    const int i  = threadIdx.x >> 3;        // 0..31
    const int j4 = (threadIdx.x & 7) * 4;   // 0..28
    const int r0 = blockIdx.y * 32;         // k block (input rows)
    const int c0 = blockIdx.x * 32;         // n block (input cols)
    f32x4 v = *(const f32x4*)(Whh + (size_t)(r0 + i) * H_ + c0 + j4);
    tile[i][j4 + 0] = v[0]; tile[i][j4 + 1] = v[1];
    tile[i][j4 + 2] = v[2]; tile[i][j4 + 3] = v[3];
    __syncthreads();
    bf16x4 o;
#pragma unroll
    for (int r = 0; r < 4; ++r) o[r] = (bf16_t)tile[j4 + r][i];
    *(bf16x4*)&g_whhT[(size_t)(c0 + i) * H_ + r0 + j4] = o;
}

// t = 0: h = tanh(x[:,0]*W_hx + b_h)  (h0 == 0) -> bf16
__global__ __launch_bounds__(256) void rnn_init(const float* __restrict__ x,
                                                const float* __restrict__ Whx,
                                                const float* __restrict__ bh) {
    const int gid = blockIdx.x * 256 + threadIdx.x;   // each does 4 cols
    const int row = gid >> 9;
    const int col = (gid & 511) << 2;
    const float xv = x[(size_t)row * T_];
    f32x4 w = *(const f32x4*)&Whx[col];
    f32x4 b = *(const f32x4*)&bh[col];
    bf16x4 o;
#pragma unroll
    for (int j = 0; j < 4; ++j) o[j] = (bf16_t)tanhf(fmaf(xv, w[j], b[j]));
    *(bf16x4*)&g_hb[0][(size_t)row * H_ + col] = o;
}

// Fused RNN step: h[db] = tanh(h[sb] @ W_hh + x[:,t]*W_hx + b_h), bf16 out.
// 64x64 tile, BK=64 (32 iters), 512 blocks (2/CU). 4-deep LDS pipeline with
// counted-vmcnt raw barriers: stages it..it+2 in flight, no per-iter drain.
// XCD swizzle: each XCD owns an 8bm x 8bn region -> 4 MB L2 working set.
__global__ __launch_bounds__(256) void rnn_step(const float* __restrict__ x,
                                                const float* __restrict__ Whx,
                                                const float* __restrict__ bh,
                                                int t, int sb, int db) {
    __shared__ __align__(16) bf16_t As[4][64 * 64];   // 8 KB per stage
    __shared__ __align__(16) bf16_t Bs[4][64 * 64];   // total 64 KB

    const int tid  = threadIdx.x;
    const int lane = tid & 63;
    const int wave = tid >> 6;
    // XCD-region swizzle: xcd = li&7 owns bm in [(x>>2)*8,+8), bn in [(x&3)*8,+8)
    const int li = blockIdx.x;
    const int xsw = li & 7;
    const int j   = li >> 3;
    const int bm = ((xsw >> 2) << 3) | (j & 7);       // 0..15
    const int bn = ((xsw & 3) << 3) | (j >> 3);       // 0..31

    const int wm = (wave & 1) * 32, wn = (wave >> 1) * 32;
    const int fr = lane & 15, fq = lane >> 4;

    // staging: thread handles rows srow, srow+32; k-chunk swizzled by row.
    const int srow = tid >> 3;              // 0..31
    const int klin = tid & 7;               // linear chunk slot in LDS
    const int kc   = klin ^ (srow & 7);     // global chunk landing there
    const bf16_t* ga = g_hb[sb] + (size_t)(bm * 64 + srow) * H_ + kc * 8;
    const bf16_t* gb = g_whhT  + (size_t)(bn * 64 + srow) * H_ + kc * 8;

    // prologue: stages 0,1,2 (12 loads/thread in flight)
#pragma unroll
    for (int s = 0; s < 3; ++s) {
        gload16(ga + s * 64,           &As[s][tid * 8]);
        gload16(ga + s * 64 + 32 * H_, &As[s][(tid + 256) * 8]);
        gload16(gb + s * 64,           &Bs[s][tid * 8]);
        gload16(gb + s * 64 + 32 * H_, &Bs[s][(tid + 256) * 8]);
    }
    const bf16_t* gpa = ga + 3 * 64;   // next stage to issue
    const bf16_t* gpb = gb + 3 * 64;

    f32x4 acc[2][2];
#pragma unroll
    for (int i = 0; i < 2; ++i)
#pragma unroll
        for (int jj = 0; jj < 2; ++jj) acc[i][jj] = (f32x4)(0.f);

    // frag LDS offsets (elems): row*64 + (c8 ^ (row&7))*8, c8 = cc*4 + fq
    const int arow0 = wm + fr, brow0 = wn + fr;
    int aoff[2][2], boff[2][2];
#pragma unroll
    for (int i = 0; i < 2; ++i)
#pragma unroll
        for (int cc = 0; cc < 2; ++cc) {
            const int ar = arow0 + i * 16, br = brow0 + i * 16;
            aoff[i][cc] = ar * 64 + (((cc * 4 + fq) ^ (ar & 7)) * 8);
            boff[i][cc] = br * 64 + (((cc * 4 + fq) ^ (br & 7)) * 8);
        }

#define COMPUTE(SLOT)                                                        \
    {                                                                        \
        bf16x8 af[2][2], bfv[2][2];                                          \
        _Pragma("unroll")                                                    \
        for (int i = 0; i < 2; ++i)                                          \
            _Pragma("unroll")                                                \
            for (int cc = 0; cc < 2; ++cc) {                                 \
                af[i][cc]  = *(const bf16x8*)&As[SLOT][aoff[i][cc]];         \
                bfv[i][cc] = *(const bf16x8*)&Bs[SLOT][boff[i][cc]];         \
            }                                                                \
        _Pragma("unroll")                                                    \
        for (int cc = 0; cc < 2; ++cc)                                       \
            _Pragma("unroll")                                                \
            for (int i = 0; i < 2; ++i)                                      \
                _Pragma("unroll")                                            \
                for (int jj = 0; jj < 2; ++jj)                               \
                    acc[i][jj] = __builtin_amdgcn_mfma_f32_16x16x32_bf16(    \
                        af[i][cc], bfv[jj][cc], acc[i][jj], 0, 0, 0);        \
    }

    // iters 0..27: steady state (issue stage it+3 into slot (it+3)&3)
    for (int g = 0; g < 7; ++g) {
#pragma unroll
        for (int u = 0; u < 4; ++u) {
            wait_vm_barrier<8>();          // stage `it` resident; it+1,it+2 fly
            const int ns = (u + 3) & 3;
            gload16(gpa,           &As[ns][tid * 8]);
            gload16(gpa + 32 * H_, &As[ns][(tid + 256) * 8]);
            gload16(gpb,           &Bs[ns][tid * 8]);
            gload16(gpb + 32 * H_, &Bs[ns][(tid + 256) * 8]);
            gpa += 64; gpb += 64;
            COMPUTE(u);
        }
    }
    // it = 28: issue final stage 31 (slot 3), compute slot 0
    wait_vm_barrier<8>();
    gload16(gpa,           &As[3][tid * 8]);
    gload16(gpa + 32 * H_, &As[3][(tid + 256) * 8]);
    gload16(gpb,           &Bs[3][tid * 8]);
    gload16(gpb + 32 * H_, &Bs[3][(tid + 256) * 8]);
    COMPUTE(0);
    // it = 29..31: drain tail
    wait_vm_barrier<8>();
    COMPUTE(1);
    wait_vm_barrier<4>();
    COMPUTE(2);
    wait_vm_barrier<0>();
    COMPUTE(3);
#undef COMPUTE

    // epilogue: + x_t*W_hx + b_h, tanh, bf16 store
    bf16_t* __restrict__ hn = g_hb[db];
    float xv[2][4];
#pragma unroll
    for (int i = 0; i < 2; ++i) {
        const int row0 = bm * 64 + wm + i * 16 + fq * 4;
#pragma unroll
        for (int r = 0; r < 4; ++r) xv[i][r] = x[(size_t)(row0 + r) * T_ + t];
    }
#pragma unroll
    for (int jj = 0; jj < 2; ++jj) {
        const int col = bn * 64 + wn + jj * 16 + fr;
        const float wv = Whx[col];
        const float bv = bh[col];
#pragma unroll
        for (int i = 0; i < 2; ++i) {
            const int row0 = bm * 64 + wm + i * 16 + fq * 4;
#pragma unroll
            for (int r = 0; r < 4; ++r)
                hn[(size_t)(row0 + r) * H_ + col] =
                    (bf16_t)tanhf(acc[i][jj][r] + xv[i][r] * wv + bv);
        }
    }
}

// p = h_T @ W_ph + b_p : one wave per batch row, fp32 accumulate.
__global__ __launch_bounds__(64) void rnn_proj(const float* __restrict__ Wph,
                                               const float* __restrict__ bp,
                                               float* __restrict__ out, int sb) {
    const int b = blockIdx.x;
    const int l = threadIdx.x;
    const bf16_t* h = g_hb[sb] + (size_t)b * H_;
    float acc[C_];
#pragma unroll
    for (int c = 0; c < C_; ++c) acc[c] = 0.f;
    for (int k = l; k < H_; k += 64) {
        const float hv = (float)h[k];
#pragma unroll
        for (int c = 0; c < C_; ++c)
            acc[c] = fmaf(hv, Wph[k * C_ + c], acc[c]);
    }
#pragma unroll
    for (int off = 32; off > 0; off >>= 1)
#pragma unroll
        for (int c = 0; c < C_; ++c) acc[c] += __shfl_down(acc[c], off);
    if (l == 0) {
#pragma unroll
        for (int c = 0; c < C_; ++c) out[b * C_ + c] = acc[c] + bp[c];
    }
}

extern "C" void kernel_launch(void* const* d_in, const int* in_sizes, int n_in,
                              void* d_out, int out_size, void* d_ws, size_t ws_size,
                              hipStream_t stream) {
    const float* x   = (const float*)d_in[0];   // [1024,128]
    const float* Whx = (const float*)d_in[1];   // [1,2048]
    const float* Whh = (const float*)d_in[2];   // [2048,2048]
    const float* bh  = (const float*)d_in[3];   // [2048]
    const float* Wph = (const float*)d_in[4];   // [2048,10]
    const float* bp  = (const float*)d_in[5];   // [1,10]
    float* out = (float*)d_out;                 // [1024,10]

    prep_whhT<<<dim3(64, 64), 256, 0, stream>>>(Whh);
    rnn_init<<<(B_ * H_ / 4) / 256, 256, 0, stream>>>(x, Whx, bh);

    int src = 0;
    for (int t = 1; t < T_; ++t) {
        rnn_step<<<512, 256, 0, stream>>>(x, Whx, bh, t, src, 1 - src);
        src = 1 - src;
    }
    rnn_proj<<<B_, 64, 0, stream>>>(Wph, bp, out, src);
}